// Round 12
// baseline (111.641 us; speedup 1.0000x reference)
//
#include <hip/hip_runtime.h>
#include <hip/hip_bf16.h>

// PositionalBias: pbv[n,j,h,d] = sum_{l=1..2046} w[h,|j-l|] * v[n,l,h,d]  (j in 1..2046, else 0)
//                 z_pb[l,h]    = sum_{j=1..2046} w[h,|l-j|]               (l in 1..2046, else 0)
// B=4, S=2048, H=12, D=64. Outputs fp32: pbv (6291456) then z_pb (24576).
//
// PRIMARY PATH: ONE 768-block fused kernel with fine-grained producer->consumer flags:
//   each block: [transpose chunk bx] (+ g_wt chunk if bx<192, zpb if 192<=bx<204)
//               -> threadfence + per-slice/per-h atomic signal
//               -> spin ONLY on own deps (16 vt chunks of its slice, 16 wt chunks of its h)
//               -> R11 asm-ring gemm.
//   Early slices start MFMAs while late transpose chunks still run -> prep hides under
//   gemm ramp; one launch gap removed. Deadlock-free iff all 768 blocks co-resident
//   (grid == 3/CU x 256 CU, launch_bounds(256,3), LDS 36.9KB); verified at first call via
//   hipOccupancyMaxActiveBlocksPerMultiprocessor, else FALLBACK to the proven R11
//   two-dispatch path. Flags self-reset (last consumer zeroes) -> graph-replay safe.

typedef short short8 __attribute__((ext_vector_type(8)));   // 8 x bf16 bits (4 VGPRs)
typedef float floatx4 __attribute__((ext_vector_type(4)));  // MFMA accumulator
typedef unsigned uint4_ __attribute__((ext_vector_type(4)));

#define QN 4352   // A-table fragment slots per h; max read = (2047-0)+2303 = 4350

__device__ __attribute__((aligned(16))) short g_vt[4 * 12 * 64 * 2048];  // 12.6 MB
__device__ __attribute__((aligned(16))) short g_wt[12 * QN * 8];         // 835 KB
__device__ int vt_cnt[48];   // transpose chunks done per (n,h) slice (16 each)
__device__ int wt_cnt[12];   // g_wt chunks done per h (16 each)
__device__ int vt_done[48];  // consumers passed (16 each) -> last resets
__device__ int wt_done[12];  // consumers passed (64 each) -> last resets

__device__ __forceinline__ unsigned short f2bf(float f) {
  union { __hip_bfloat16 b; unsigned short u; } cv;
  cv.b = __float2bfloat16(f);  // RNE
  return cv.u;
}

// ---- producer: A fragment table chunk (idx = h*16 + c) ----
__device__ __forceinline__ void do_gwt(int idx, int tid, const float* __restrict__ w) {
  const int h = idx >> 4;
  const int c = idx & 15;
  const float* wh = w + (size_t)h * 2048;
  short* F = g_wt + (size_t)h * QN * 8;
  const int qs = c * 272;
  for (int q = qs + tid; q < qs + 272; q += 256) {
    unsigned short buf[8] __attribute__((aligned(16)));
    #pragma unroll
    for (int i = 0; i < 8; ++i) {
      int t = 2174 - q - i;
      int a = t < 0 ? -t : t;
      buf[i] = (a <= 2045) ? f2bf(wh[a]) : (unsigned short)0;
    }
    *(short8*)&F[(size_t)q * 8] = *(const short8*)buf;
  }
}

// ---- producer: v -> g_vt transpose chunk (bx in 0..767) ----
__device__ __forceinline__ void do_transpose(int bx, int tid, unsigned* tls,
                                             const float* __restrict__ v) {
  const int chunk = bx & 15;            // 16 chunks of 128 l
  const int slice = bx >> 4;            // 0..47 = n*12+h
  const int n = slice / 12, h = slice - n * 12;
  const int lane = tid & 63;            // d on read side
  const int wv   = tid >> 6;            // 0..3
  const int lbase = chunk * 128 + wv * 32;

  const float* src = v + (((size_t)n * 2048 + lbase) * 12 + h) * 64 + lane;
  #pragma unroll
  for (int kk = 0; kk < 16; ++kk) {
    float f0 = src[(size_t)(2 * kk)     * 768];
    float f1 = src[(size_t)(2 * kk + 1) * 768];
    int l = lbase + 2 * kk;
    unsigned lo = (l == 0)        ? 0u : (unsigned)f2bf(f0);
    unsigned hi = (l + 1 == 2047) ? 0u : (unsigned)f2bf(f1);
    tls[lane * 65 + wv * 16 + kk] = lo | (hi << 16);
  }
  __syncthreads();

  const int r = tid >> 2;               // d-row on store side
  const int m = tid & 3;                // 64B segment within row
  unsigned xbuf[16];
  #pragma unroll
  for (int k = 0; k < 16; ++k) xbuf[k] = tls[r * 65 + m * 16 + k];
  unsigned* dstu = (unsigned*)(g_vt + (((size_t)n * 12 + h) * 64 + r) * 2048 +
                               (size_t)chunk * 128) + m * 16;
  #pragma unroll
  for (int k4 = 0; k4 < 4; ++k4) {
    uint4_ val = {xbuf[k4 * 4], xbuf[k4 * 4 + 1], xbuf[k4 * 4 + 2], xbuf[k4 * 4 + 3]};
    *(uint4_*)&dstu[k4 * 4] = val;
  }
}

// ---- independent: z_pb for head h ----
__device__ __forceinline__ void do_zpb(int h, int tid, float* zls, float* wsum,
                                       const float* __restrict__ w,
                                       float* __restrict__ out) {
  float* wvv = zls;          // [2048]
  float* pfx = zls + 2048;   // [2048]
  const float* wh = w + (size_t)h * 2048;
  float* zout = out + 6291456;
  for (int i = tid; i < 2048; i += 256) wvv[i] = (i < 2046) ? wh[i] : 0.f;
  __syncthreads();
  const int base = tid * 8;
  float run0 = 0.f;
  #pragma unroll
  for (int k = 0; k < 8; ++k) run0 += wvv[base + k];
  float x = run0;
  #pragma unroll
  for (int dd = 1; dd < 64; dd <<= 1) {
    float y = __shfl_up(x, dd);
    if ((tid & 63) >= dd) x += y;
  }
  if ((tid & 63) == 63) wsum[tid >> 6] = x;
  __syncthreads();
  const int wid4 = tid >> 6;
  float woff = 0.f;
  #pragma unroll
  for (int u = 0; u < 3; ++u) { float t = wsum[u]; if (u < wid4) woff += t; }
  float pr = x + woff - run0;
  #pragma unroll
  for (int k = 0; k < 8; ++k) { pr += wvv[base + k]; pfx[base + k] = pr; }
  __syncthreads();
  for (int i = tid; i < 2046; i += 256) {
    float z = pfx[i] + pfx[2045 - i] - wvv[0];
    zout[(size_t)(i + 1) * 12 + h] = z;
  }
  if (tid == 0) { zout[h] = 0.f; zout[(size_t)2047 * 12 + h] = 0.f; }
}

// ---- consumer: R11 asm-ring Toeplitz GEMM (128j x 64nd per block) ----
__device__ void do_gemm(int bx, int tid, short* Als, float* __restrict__ out) {
  const int slice = bx % 48;          // (h, ndt); same-slice blocks 48 apart -> same XCD
  const int jt    = bx / 48;          // 16 j-tiles
  const int ndt = slice & 3;
  const int h   = slice >> 2;
  const int lane = tid & 63;
  const int wid  = tid >> 6;
  const int lm = lane & 15, quad = lane >> 4;
  const int jb = jt * 128;
  const int d  = wid * 16 + lm;       // wave owns a 16-d strip

  const short* vtb = g_vt + (((size_t)ndt * 12 + h) * 64 + d) * 2048;

  short8 afr[16];      // A ring: slot = D & 15, D = 4T + g + 7 (prefetch disjoint mod 16)
  short8 Bp0[4], Bp1[4];

  // prologue B pairs t=0,1 (plain loads; drained by the barrier below)
  Bp0[0] = *(const short8*)&vtb[quad * 8];
  Bp1[0] = *(const short8*)&vtb[quad * 8 + 32];
  Bp0[1] = *(const short8*)&vtb[64 + quad * 8];
  Bp1[1] = *(const short8*)&vtb[64 + quad * 8 + 32];

  // copy this block's A-window g_wt[h][qbase .. qbase+2303] -> LDS (coalesced)
  const short* wsrc = g_wt + (size_t)h * QN * 8 + (size_t)(2047 - jb) * 8;
  #pragma unroll
  for (int k = 0; k < 9; ++k) {
    *(short8*)&Als[(size_t)(k * 256 + tid) * 8] =
        *(const short8*)&wsrc[(size_t)(k * 256 + tid) * 8];
  }
  __syncthreads();   // drains vmcnt/lgkmcnt: clean counter state at loop entry

  const int abase = 127 + quad * 8 - lm;
  unsigned az0 = (unsigned)(unsigned long long)(&Als[0]) + (unsigned)(abase * 16) - 1792u;
  unsigned long long vb0 = (unsigned long long)(const void*)(vtb + quad * 8);

  floatx4 acc[8];
  #pragma unroll
  for (int ma = 0; ma < 8; ++ma) acc[ma] = (floatx4){0.f, 0.f, 0.f, 0.f};

#define A_PRO(D) \
  asm volatile("ds_read_b128 %0, %1 offset:%2" : "=v"(afr[D]) : "v"(az0), "n"(256 * (D)));
  A_PRO(0) A_PRO(1) A_PRO(2) A_PRO(3) A_PRO(4)
  A_PRO(5) A_PRO(6) A_PRO(7) A_PRO(8) A_PRO(9)
#undef A_PRO

#define G_ITER(T)                                                                        \
  {                                                                                      \
    if ((T) < 30) {                                                                      \
      asm volatile("global_load_dwordx4 %0, %1, off offset:%2"                           \
                   : "=v"(Bp0[((T) + 2) & 3])                                            \
                   : "v"(vb0), "n"((((T) < 30 ? (T) + 2 : 0) * 128)));                   \
      asm volatile("global_load_dwordx4 %0, %1, off offset:%2"                           \
                   : "=v"(Bp1[((T) + 2) & 3])                                            \
                   : "v"(vb0), "n"((((T) < 30 ? (T) + 2 : 0) * 128 + 64)));              \
    }                                                                                    \
    if ((T) < 31) {                                                                      \
      asm volatile("ds_read_b128 %0, %1 offset:%2"                                       \
                   : "=v"(afr[(4 * (T) + 10) & 15])                                      \
                   : "v"(az0), "n"(((T) < 31 ? 1024 * (T) + 2560 : 0)));                 \
      asm volatile("ds_read_b128 %0, %1 offset:%2"                                       \
                   : "=v"(afr[(4 * (T) + 11) & 15])                                      \
                   : "v"(az0), "n"(((T) < 31 ? 1024 * (T) + 2816 : 0)));                 \
      asm volatile("ds_read_b128 %0, %1 offset:%2"                                       \
                   : "=v"(afr[(4 * (T) + 12) & 15])                                      \
                   : "v"(az0), "n"(((T) < 31 ? 1024 * (T) + 3072 : 0)));                 \
      asm volatile("ds_read_b128 %0, %1 offset:%2"                                       \
                   : "=v"(afr[(4 * (T) + 13) & 15])                                      \
                   : "v"(az0), "n"(((T) < 31 ? 1024 * (T) + 3328 : 0)));                 \
    }                                                                                    \
    if ((T) < 30)       asm volatile("s_waitcnt vmcnt(4) lgkmcnt(4)" ::: "memory");      \
    else if ((T) == 30) asm volatile("s_waitcnt vmcnt(2) lgkmcnt(4)" ::: "memory");      \
    else                asm volatile("s_waitcnt vmcnt(0) lgkmcnt(0)" ::: "memory");      \
    __builtin_amdgcn_sched_barrier(0);                                                   \
    __builtin_amdgcn_s_setprio(1);                                                       \
    _Pragma("unroll")                                                                    \
    for (int ma = 0; ma < 8; ++ma)  /* kc=0: g=-ma -> D=4T+7-ma */                       \
      acc[ma] = __builtin_amdgcn_mfma_f32_16x16x32_bf16(                                 \
          afr[(4 * (T) + 7 - ma) & 15], Bp0[(T) & 3], acc[ma], 0, 0, 0);                 \
    _Pragma("unroll")                                                                    \
    for (int ma = 0; ma < 8; ++ma)  /* kc=1: g=2-ma -> D=4T+9-ma */                      \
      acc[ma] = __builtin_amdgcn_mfma_f32_16x16x32_bf16(                                 \
          afr[(4 * (T) + 9 - ma) & 15], Bp1[(T) & 3], acc[ma], 0, 0, 0);                 \
    __builtin_amdgcn_s_setprio(0);                                                       \
  }

  G_ITER(0)  G_ITER(1)  G_ITER(2)  G_ITER(3)  G_ITER(4)  G_ITER(5)  G_ITER(6)  G_ITER(7)
  G_ITER(8)  G_ITER(9)  G_ITER(10) G_ITER(11) G_ITER(12) G_ITER(13) G_ITER(14) G_ITER(15)
  G_ITER(16) G_ITER(17) G_ITER(18) G_ITER(19) G_ITER(20) G_ITER(21) G_ITER(22) G_ITER(23)
  G_ITER(24) G_ITER(25) G_ITER(26) G_ITER(27) G_ITER(28) G_ITER(29) G_ITER(30) G_ITER(31)
#undef G_ITER

  float* obase = out + (size_t)ndt * 1572864 + (size_t)h * 64 + d;
  #pragma unroll
  for (int ma = 0; ma < 8; ++ma) {
    floatx4 cc = acc[ma];
    #pragma unroll
    for (int r = 0; r < 4; ++r) {
      int j = jb + ma * 16 + quad * 4 + r;
      float val = (j == 0 || j == 2047) ? 0.f : cc[r];
      obase[(size_t)j * 768] = val;
    }
  }
}

// ================= PRIMARY: fused producer/consumer kernel (768 blocks) =================
__global__ __launch_bounds__(256, 3) void fused_kernel(const float* __restrict__ v,
                                                       const float* __restrict__ w,
                                                       float* __restrict__ out) {
  __shared__ __attribute__((aligned(16))) char smem[36864];
  const int bx  = blockIdx.x;
  const int tid = threadIdx.x;

  // ---- produce: own transpose chunk, then signal its slice ----
  do_transpose(bx, tid, (unsigned*)smem, v);
  __threadfence();
  __syncthreads();
  if (tid == 0) atomicAdd(&vt_cnt[bx >> 4], 1);

  // ---- produce: g_wt chunk (blocks 0..191), signal its h ----
  if (bx < 192) {
    do_gwt(bx, tid, w);
    __threadfence();
    __syncthreads();
    if (tid == 0) atomicAdd(&wt_cnt[bx >> 4], 1);
  } else if (bx < 204) {   // ---- independent z_pb (blocks 192..203) ----
    __syncthreads();       // smem handoff from transpose
    do_zpb(bx - 192, tid, (float*)smem, (float*)(smem + 16384), w, out);
  }

  // ---- consume: spin only on own dependencies ----
  const int slice = bx % 48;
  const int ndt = slice & 3, h = slice >> 2;
  const int vts = ndt * 12 + h;        // producer slice id = n*12+h
  if (tid == 0) {
    while (__hip_atomic_load(&vt_cnt[vts], __ATOMIC_RELAXED, __HIP_MEMORY_SCOPE_AGENT) < 16 ||
           __hip_atomic_load(&wt_cnt[h],  __ATOMIC_RELAXED, __HIP_MEMORY_SCOPE_AGENT) < 16)
      __builtin_amdgcn_s_sleep(2);
  }
  __syncthreads();
  __threadfence();   // acquire side

  // ---- self-resetting flags (graph-replay safe): last consumer zeroes ----
  if (tid == 0) {
    if (atomicAdd(&vt_done[vts], 1) == 15) {
      __hip_atomic_store(&vt_cnt[vts], 0, __ATOMIC_RELAXED, __HIP_MEMORY_SCOPE_AGENT);
      __hip_atomic_store(&vt_done[vts], 0, __ATOMIC_RELAXED, __HIP_MEMORY_SCOPE_AGENT);
    }
    if (atomicAdd(&wt_done[h], 1) == 63) {
      __hip_atomic_store(&wt_cnt[h], 0, __ATOMIC_RELAXED, __HIP_MEMORY_SCOPE_AGENT);
      __hip_atomic_store(&wt_done[h], 0, __ATOMIC_RELAXED, __HIP_MEMORY_SCOPE_AGENT);
    }
  }
  __syncthreads();   // smem handoff (zpb blocks) before gemm reuses it

  do_gemm(bx, tid, (short*)smem, out);
}

// ================= FALLBACK: proven R11 two-dispatch path =================
__global__ __launch_bounds__(256) void prep_kernel(const float* __restrict__ v,
                                                   const float* __restrict__ w,
                                                   float* __restrict__ out) {
  __shared__ __attribute__((aligned(16))) char smem[36864];
  const int bx  = blockIdx.x;
  const int tid = threadIdx.x;
  if (bx >= 780) { do_gwt(bx - 780, tid, w); return; }
  if (bx >= 768) { do_zpb(bx - 768, tid, (float*)smem, (float*)(smem + 16384), w, out); return; }
  do_transpose(bx, tid, (unsigned*)smem, v);
}

__global__ __launch_bounds__(256, 3) void gemm_kernel(float* __restrict__ out) {
  __shared__ __attribute__((aligned(16))) char smem[36864];
  do_gemm(blockIdx.x, threadIdx.x, (short*)smem, out);
}

extern "C" void kernel_launch(void* const* d_in, const int* in_sizes, int n_in,
                              void* d_out, int out_size, void* d_ws, size_t ws_size,
                              hipStream_t stream) {
  const float* v = (const float*)d_in[0];   // (4,2048,12,64) fp32
  const float* w = (const float*)d_in[1];   // (12,2048) fp32
  float* out = (float*)d_out;               // pbv (6291456) + z_pb (24576) fp32

  static int fused_ok = -1;
  if (fused_ok < 0) {
    int nb = 0;
    if (hipOccupancyMaxActiveBlocksPerMultiprocessor(&nb, fused_kernel, 256, 0) != hipSuccess)
      nb = 0;
    fused_ok = (nb >= 3) ? 1 : 0;     // all 768 blocks co-resident -> spin-flags safe
  }

  if (fused_ok) {
    fused_kernel<<<dim3(768), 256, 0, stream>>>(v, w, out);
  } else {
    prep_kernel<<<dim3(972), 256, 0, stream>>>(v, w, out);
    gemm_kernel<<<dim3(768), 256, 0, stream>>>(out);
  }
}

// Round 13
// 106.907 us; speedup vs baseline: 1.0443x; 1.0443x over previous
//
#include <hip/hip_runtime.h>
#include <hip/hip_bf16.h>

// PositionalBias: pbv[n,j,h,d] = sum_{l=1..2046} w[h,|j-l|] * v[n,l,h,d]  (j in 1..2046, else 0)
//                 z_pb[l,h]    = sum_{j=1..2046} w[h,|l-j|]               (l in 1..2046, else 0)
// B=4, S=2048, H=12, D=64. Outputs fp32: pbv (6291456) then z_pb (24576).
//
// TWO dispatches (session-best structure, R11):
//  1) prep_kernel (972 blocks): 0..767 LDS-transpose v -> g_vt[n][h][d][l] bf16 (borders
//     zeroed); 768..779 z_pb; 780..971 A-fragment table g_wt (12 h x 16 chunks).
//  2) gemm_kernel (768 blocks): A-window LDS copy once, then 32 macro-unrolled iters with
//     COMPILE-TIME ring buffers: afr[16] A-slots (slot = D mod 16, D = 4T+g+7) and Bp[4]
//     B-pairs (consume T&3, load (T+2)&3). Every asm offset is a literal immediate ->
//     per iter exactly {2 global_load_dwordx4 + 4 ds_read_b128 + 1 counted s_waitcnt +
//     sched_barrier + 16 MFMA}. Zero v_mov rotation, zero address VALU.

typedef short short8 __attribute__((ext_vector_type(8)));   // 8 x bf16 bits (4 VGPRs)
typedef float floatx4 __attribute__((ext_vector_type(4)));  // MFMA accumulator
typedef unsigned uint4_ __attribute__((ext_vector_type(4)));

#define QN 4352   // A-table fragment slots per h; max read = (2047-0)+2303 = 4350

__device__ __attribute__((aligned(16))) short g_vt[4 * 12 * 64 * 2048];  // 12.6 MB
__device__ __attribute__((aligned(16))) short g_wt[12 * QN * 8];         // 835 KB

__device__ __forceinline__ unsigned short f2bf(float f) {
  union { __hip_bfloat16 b; unsigned short u; } cv;
  cv.b = __float2bfloat16(f);  // RNE
  return cv.u;
}

// ---------------- dispatch 1: v -> g_vt (LDS transpose), z_pb, w -> g_wt ----------------
__global__ __launch_bounds__(256) void prep_kernel(const float* __restrict__ v,
                                                   const float* __restrict__ w,
                                                   float* __restrict__ out) {
  __shared__ unsigned tls[64 * 65];   // transpose tile: [d][l-pair], pad->2-way only
  __shared__ float zls[4096];
  __shared__ float wsum[4];

  const int bx  = blockIdx.x;
  const int tid = threadIdx.x;

  if (bx >= 780) {   // ---- A fragment table, 192 blocks: (h, 272-slot chunk) ----
    const int idx = bx - 780;
    const int h = idx >> 4;
    const int c = idx & 15;
    const float* wh = w + (size_t)h * 2048;
    short* F = g_wt + (size_t)h * QN * 8;
    const int qs = c * 272;
    for (int q = qs + tid; q < qs + 272; q += 256) {
      unsigned short buf[8] __attribute__((aligned(16)));
      #pragma unroll
      for (int i = 0; i < 8; ++i) {
        int t = 2174 - q - i;
        int a = t < 0 ? -t : t;
        buf[i] = (a <= 2045) ? f2bf(wh[a]) : (unsigned short)0;
      }
      *(short8*)&F[(size_t)q * 8] = *(const short8*)buf;
    }
    return;
  }

  if (bx >= 768) {   // ---- zpb: z[i+1] = P[i] + P[2045-i] - w[h,0] ----
    const int h = bx - 768;
    float* wvv = zls;          // [2048]
    float* pfx = zls + 2048;   // [2048]
    const float* wh = w + (size_t)h * 2048;
    float* zout = out + 6291456;
    for (int i = tid; i < 2048; i += 256) wvv[i] = (i < 2046) ? wh[i] : 0.f;
    __syncthreads();
    const int base = tid * 8;
    float run0 = 0.f;
    #pragma unroll
    for (int k = 0; k < 8; ++k) run0 += wvv[base + k];
    float x = run0;
    #pragma unroll
    for (int dd = 1; dd < 64; dd <<= 1) {
      float y = __shfl_up(x, dd);
      if ((tid & 63) >= dd) x += y;
    }
    if ((tid & 63) == 63) wsum[tid >> 6] = x;
    __syncthreads();
    const int wid4 = tid >> 6;
    float woff = 0.f;
    #pragma unroll
    for (int u = 0; u < 3; ++u) { float t = wsum[u]; if (u < wid4) woff += t; }
    float pr = x + woff - run0;
    #pragma unroll
    for (int k = 0; k < 8; ++k) { pr += wvv[base + k]; pfx[base + k] = pr; }
    __syncthreads();
    for (int i = tid; i < 2046; i += 256) {
      float z = pfx[i] + pfx[2045 - i] - wvv[0];
      zout[(size_t)(i + 1) * 12 + h] = z;
    }
    if (tid == 0) { zout[h] = 0.f; zout[(size_t)2047 * 12 + h] = 0.f; }
    return;
  }

  // ---- transpose: block = (n, h, 128-l chunk). ----
  const int chunk = bx & 15;            // 16 chunks of 128 l
  const int slice = bx >> 4;            // 0..47
  const int n = slice / 12, h = slice - n * 12;
  const int lane = tid & 63;            // d on read side
  const int wv   = tid >> 6;            // 0..3
  const int lbase = chunk * 128 + wv * 32;

  const float* src = v + (((size_t)n * 2048 + lbase) * 12 + h) * 64 + lane;
  #pragma unroll
  for (int kk = 0; kk < 16; ++kk) {
    float f0 = src[(size_t)(2 * kk)     * 768];
    float f1 = src[(size_t)(2 * kk + 1) * 768];
    int l = lbase + 2 * kk;
    unsigned lo = (l == 0)        ? 0u : (unsigned)f2bf(f0);
    unsigned hi = (l + 1 == 2047) ? 0u : (unsigned)f2bf(f1);
    tls[lane * 65 + wv * 16 + kk] = lo | (hi << 16);
  }
  __syncthreads();

  const int r = tid >> 2;               // d-row on store side
  const int m = tid & 3;                // 64B segment within row
  unsigned xbuf[16];
  #pragma unroll
  for (int k = 0; k < 16; ++k) xbuf[k] = tls[r * 65 + m * 16 + k];
  unsigned* dstu = (unsigned*)(g_vt + (((size_t)n * 12 + h) * 64 + r) * 2048 +
                               (size_t)chunk * 128) + m * 16;
  #pragma unroll
  for (int k4 = 0; k4 < 4; ++k4) {
    uint4_ val = {xbuf[k4 * 4], xbuf[k4 * 4 + 1], xbuf[k4 * 4 + 2], xbuf[k4 * 4 + 3]};
    *(uint4_*)&dstu[k4 * 4] = val;
  }
}

// ---------------- dispatch 2: Toeplitz GEMM, 128j x 64nd per block ----------------------
__global__ __launch_bounds__(256, 3) void gemm_kernel(float* __restrict__ out) {
  __shared__ __attribute__((aligned(16))) short Als[2304 * 8];  // 36,864 B

  const int bx  = blockIdx.x;
  const int tid = threadIdx.x;

  const int slice = bx % 48;          // (h, ndt); same-slice blocks 48 apart -> same XCD
  const int jt    = bx / 48;          // 16 j-tiles
  const int ndt = slice & 3;
  const int h   = slice >> 2;
  const int lane = tid & 63;
  const int wid  = tid >> 6;
  const int lm = lane & 15, quad = lane >> 4;
  const int jb = jt * 128;
  const int d  = wid * 16 + lm;       // wave owns a 16-d strip

  // B: bf16 v^T row (borders pre-zeroed in prep). One dwordx4 IS the B-fragment.
  const short* vtb = g_vt + (((size_t)ndt * 12 + h) * 64 + d) * 2048;

  short8 afr[16];      // A ring: slot = D & 15, D = 4T + g + 7 (prefetch disjoint mod 16)
  short8 Bp0[4], Bp1[4];

  // prologue B pairs t=0,1 (plain loads; drained by the barrier below)
  Bp0[0] = *(const short8*)&vtb[quad * 8];
  Bp1[0] = *(const short8*)&vtb[quad * 8 + 32];
  Bp0[1] = *(const short8*)&vtb[64 + quad * 8];
  Bp1[1] = *(const short8*)&vtb[64 + quad * 8 + 32];

  // copy this block's A-window g_wt[h][qbase .. qbase+2303] -> LDS (coalesced)
  const short* wsrc = g_wt + (size_t)h * QN * 8 + (size_t)(2047 - jb) * 8;
  #pragma unroll
  for (int k = 0; k < 9; ++k) {
    *(short8*)&Als[(size_t)(k * 256 + tid) * 8] =
        *(const short8*)&wsrc[(size_t)(k * 256 + tid) * 8];
  }
  __syncthreads();   // drains vmcnt/lgkmcnt: clean counter state at loop entry

  // A byte address: frag at diagonal D -> az0 + 256*D, az0 = &Als + abase*16 - 1792.
  // abase = 127 + quad*8 - lm >= 112 -> az0 >= LDS base. Max offset 256*133 = 34048.
  const int abase = 127 + quad * 8 - lm;
  unsigned az0 = (unsigned)(unsigned long long)(&Als[0]) + (unsigned)(abase * 16) - 1792u;
  // B base: pair T at vb0 + T*128 (+64 for kc=1). Max literal 31*128+64 = 4032.
  unsigned long long vb0 = (unsigned long long)(const void*)(vtb + quad * 8);

  floatx4 acc[8];
  #pragma unroll
  for (int ma = 0; ma < 8; ++ma) acc[ma] = (floatx4){0.f, 0.f, 0.f, 0.f};

  // prologue A window: D = 0..9 (g = -7..2 at T=0)
#define A_PRO(D) \
  asm volatile("ds_read_b128 %0, %1 offset:%2" : "=v"(afr[D]) : "v"(az0), "n"(256 * (D)));
  A_PRO(0) A_PRO(1) A_PRO(2) A_PRO(3) A_PRO(4)
  A_PRO(5) A_PRO(6) A_PRO(7) A_PRO(8) A_PRO(9)
#undef A_PRO

  // one iteration, T = compile-time literal. Order: issue B(T+2), issue A(T+1),
  // counted wait (newest 4 VMEM + newest 4 LDS may remain), fence, 16 MFMA.
#define G_ITER(T)                                                                        \
  {                                                                                      \
    if ((T) < 30) {                                                                      \
      asm volatile("global_load_dwordx4 %0, %1, off offset:%2"                           \
                   : "=v"(Bp0[((T) + 2) & 3])                                            \
                   : "v"(vb0), "n"((((T) < 30 ? (T) + 2 : 0) * 128)));                   \
      asm volatile("global_load_dwordx4 %0, %1, off offset:%2"                           \
                   : "=v"(Bp1[((T) + 2) & 3])                                            \
                   : "v"(vb0), "n"((((T) < 30 ? (T) + 2 : 0) * 128 + 64)));              \
    }                                                                                    \
    if ((T) < 31) {                                                                      \
      asm volatile("ds_read_b128 %0, %1 offset:%2"                                       \
                   : "=v"(afr[(4 * (T) + 10) & 15])                                      \
                   : "v"(az0), "n"(((T) < 31 ? 1024 * (T) + 2560 : 0)));                 \
      asm volatile("ds_read_b128 %0, %1 offset:%2"                                       \
                   : "=v"(afr[(4 * (T) + 11) & 15])                                      \
                   : "v"(az0), "n"(((T) < 31 ? 1024 * (T) + 2816 : 0)));                 \
      asm volatile("ds_read_b128 %0, %1 offset:%2"                                       \
                   : "=v"(afr[(4 * (T) + 12) & 15])                                      \
                   : "v"(az0), "n"(((T) < 31 ? 1024 * (T) + 3072 : 0)));                 \
      asm volatile("ds_read_b128 %0, %1 offset:%2"                                       \
                   : "=v"(afr[(4 * (T) + 13) & 15])                                      \
                   : "v"(az0), "n"(((T) < 31 ? 1024 * (T) + 3328 : 0)));                 \
    }                                                                                    \
    if ((T) < 30)       asm volatile("s_waitcnt vmcnt(4) lgkmcnt(4)" ::: "memory");      \
    else if ((T) == 30) asm volatile("s_waitcnt vmcnt(2) lgkmcnt(4)" ::: "memory");      \
    else                asm volatile("s_waitcnt vmcnt(0) lgkmcnt(0)" ::: "memory");      \
    __builtin_amdgcn_sched_barrier(0);                                                   \
    __builtin_amdgcn_s_setprio(1);                                                       \
    _Pragma("unroll")                                                                    \
    for (int ma = 0; ma < 8; ++ma)  /* kc=0: g=-ma -> D=4T+7-ma */                       \
      acc[ma] = __builtin_amdgcn_mfma_f32_16x16x32_bf16(                                 \
          afr[(4 * (T) + 7 - ma) & 15], Bp0[(T) & 3], acc[ma], 0, 0, 0);                 \
    _Pragma("unroll")                                                                    \
    for (int ma = 0; ma < 8; ++ma)  /* kc=1: g=2-ma -> D=4T+9-ma */                      \
      acc[ma] = __builtin_amdgcn_mfma_f32_16x16x32_bf16(                                 \
          afr[(4 * (T) + 9 - ma) & 15], Bp1[(T) & 3], acc[ma], 0, 0, 0);                 \
    __builtin_amdgcn_s_setprio(0);                                                       \
  }

  G_ITER(0)  G_ITER(1)  G_ITER(2)  G_ITER(3)  G_ITER(4)  G_ITER(5)  G_ITER(6)  G_ITER(7)
  G_ITER(8)  G_ITER(9)  G_ITER(10) G_ITER(11) G_ITER(12) G_ITER(13) G_ITER(14) G_ITER(15)
  G_ITER(16) G_ITER(17) G_ITER(18) G_ITER(19) G_ITER(20) G_ITER(21) G_ITER(22) G_ITER(23)
  G_ITER(24) G_ITER(25) G_ITER(26) G_ITER(27) G_ITER(28) G_ITER(29) G_ITER(30) G_ITER(31)
#undef G_ITER

  // epilogue: D row = quad*4 + r (j), col = lm (d); zero rows j=0 and j=2047
  float* obase = out + (size_t)ndt * 1572864 + (size_t)h * 64 + d;
  #pragma unroll
  for (int ma = 0; ma < 8; ++ma) {
    floatx4 cc = acc[ma];
    #pragma unroll
    for (int r = 0; r < 4; ++r) {
      int j = jb + ma * 16 + quad * 4 + r;
      float val = (j == 0 || j == 2047) ? 0.f : cc[r];
      obase[(size_t)j * 768] = val;
    }
  }
}

extern "C" void kernel_launch(void* const* d_in, const int* in_sizes, int n_in,
                              void* d_out, int out_size, void* d_ws, size_t ws_size,
                              hipStream_t stream) {
  const float* v = (const float*)d_in[0];   // (4,2048,12,64) fp32
  const float* w = (const float*)d_in[1];   // (12,2048) fp32
  float* out = (float*)d_out;               // pbv (6291456) + z_pb (24576) fp32
  prep_kernel<<<dim3(972), 256, 0, stream>>>(v, w, out);
  gemm_kernel<<<dim3(768), 256, 0, stream>>>(out);
}